// Round 2
// baseline (9.630 us; speedup 1.0000x reference)
//
#include <hip/hip_runtime.h>

// GlimpseSensor: rho[b,p,i,j,c] = images[b, fy - 8*2^p + i*2^p, fx - 8*2^p + j*2^p, c]
// (zero outside the image), fixations[b] = (fy, fx) stored as float32 at the tail.
// Legacy TF bilinear with integer scale factor == exact strided subsampling.
//
// Round 1: float4 output stores. Each patch row is GW*CC = 48 floats (div by 4),
// so a quad of 4 consecutive outputs always shares (b, p, i) -> decode once,
// y bounds-check once, gather 4 elements (contiguous for p=0).

#define BB 64
#define HH 512
#define WW 512
#define CC 3
#define GW 16
#define KK 3

#define RHO_Q (BB * KK * GW * GW * CC / 4)  // 36864 float4 quads
#define FIX_Q (BB * 2 / 4)                  // 32 float4 quads

__global__ void GlimpseSensor_45767171506547_kernel(const float* __restrict__ images,
                                                    const float* __restrict__ loc,
                                                    float4* __restrict__ out4) {
    int u = blockIdx.x * blockDim.x + threadIdx.x;
    if (u < RHO_Q) {
        // quad u covers rho flat elements [4u, 4u+4): row-offset r0 = (u%12)*4,
        // then i, p, b from u/12.
        int r0 = (u % 12) * 4;
        int t = u / 12;
        int i = t & (GW - 1); t >>= 4;
        int p = t % KK;
        int b = t / KK;

        float l0 = loc[b * 2 + 0];
        float l1 = loc[b * 2 + 1];
        int fy = (int)rintf((l0 + 1.0f) * 0.5f * (float)(HH - 1));
        int fx = (int)rintf((l1 + 1.0f) * 0.5f * (float)(WW - 1));

        int step = 1 << p;       // 1, 2, 4
        int half = (GW / 2) << p;
        int y = fy - half + i * step;  // quad-uniform

        float4 v = make_float4(0.f, 0.f, 0.f, 0.f);
        if ((unsigned)y < (unsigned)HH) {
            const float* __restrict__ row = images + (size_t)(b * HH + y) * (WW * CC);
            float* vv = (float*)&v;
#pragma unroll
            for (int e = 0; e < 4; ++e) {
                int r = r0 + e;          // within-row offset, < 48
                int j = r / 3;
                int c = r - j * 3;
                int x = fx - half + j * step;
                if ((unsigned)x < (unsigned)WW) vv[e] = row[x * CC + c];
            }
        }
        out4[u] = v;
    } else if (u < RHO_Q + FIX_Q) {
        int b0 = (u - RHO_Q) * 2;  // two (fy, fx) pairs per quad
        float4 v;
        float* vv = (float*)&v;
#pragma unroll
        for (int q = 0; q < 2; ++q) {
            int b = b0 + q;
            vv[2 * q + 0] = (float)(int)rintf((loc[b * 2 + 0] + 1.0f) * 0.5f * (float)(HH - 1));
            vv[2 * q + 1] = (float)(int)rintf((loc[b * 2 + 1] + 1.0f) * 0.5f * (float)(WW - 1));
        }
        out4[u] = v;
    }
}

extern "C" void kernel_launch(void* const* d_in, const int* in_sizes, int n_in,
                              void* d_out, int out_size, void* d_ws, size_t ws_size,
                              hipStream_t stream) {
    const float* images = (const float*)d_in[0];
    const float* loc = (const float*)d_in[1];
    float4* out4 = (float4*)d_out;

    const int total = RHO_Q + FIX_Q;  // 36896
    const int block = 256;
    const int grid = (total + block - 1) / block;  // 145
    GlimpseSensor_45767171506547_kernel<<<grid, block, 0, stream>>>(images, loc, out4);
}